// Round 8
// baseline (596.064 us; speedup 1.0000x reference)
//
#include <hip/hip_runtime.h>
#include <hip/hip_cooperative_groups.h>
#include <math.h>

// SubGraphTransformer: B=8,N=512,E=256,H=8,HD=32,FF=1024,TOPK=102.
// Floyd-Warshall is dead code: surviving (top-k) entries all have dist==1
// except the diagonal (dist==0); row-constant bias cancels under softmax, so
// only topk bitmask + per-head diagonal delta (emb[1][h]-emb[2][h]) matter.
// R3: bf16 MFMA everywhere heavy. R4: pool parallelized. R5 (reverted):
// uncoalesced frag gathers. R6: frag-order global K/V -> coalesced attn.
// R7 (reverted): pairwise GEMM+LN fusion died on occupancy (1 blk/CU, 4-way
// LDS write conflicts, 128MB W re-read; MfmaUtil 1.5%).
// R8: the ~80us of inter-dispatch gaps is the target. One cooperative
// megakernel runs all post-topk phases with grid.sync() between them,
// reusing R6's proven per-phase code. Fallback to discrete launches if
// cooperative launch is rejected.

#define B_ 8
#define N_ 512
#define E_ 256
#define H_ 8
#define HD_ 32
#define TOPK_ 102

namespace cg = cooperative_groups;

typedef __attribute__((ext_vector_type(8))) short bf16x8;
typedef __attribute__((ext_vector_type(4))) float f32x4;

__device__ __forceinline__ unsigned short f2b(float f) {  // fp32->bf16 RNE
  unsigned u = __builtin_bit_cast(unsigned, f);
  return (unsigned short)((u + 0x7FFFu + ((u >> 16) & 1u)) >> 16);
}

struct SmemGemm { unsigned short Af[8 * 64 * 8]; unsigned short Wf[8 * 64 * 8]; };  // 16 KB
struct SmemAttn { unsigned int mrow[64 * 16]; unsigned short pF[4][2 * 64 * 8]; };  // 12 KB
struct SmemLN   { float red[8]; };
union SmemU { SmemGemm gm; SmemAttn at; SmemLN ln; };

struct MegaArgs {
  const unsigned short *xb, *wqkvb, *woutb, *wff1b, *wff2b;
  const unsigned int* bits;
  const float *x, *emb, *b_qkv, *b_out, *b_ff1, *b_ff2;
  const float *g1, *be1, *g2, *be2, *wp, *bp;
  unsigned short *qb, *kG, *vG, *ctxb, *x1b, *hffb;
  float *tbuf, *x1, *partial, *pwsum, *outp;
};

// ---------------- 1. fused cast + top-k (separate kernel: wants 5888 blocks) ----
__global__ __launch_bounds__(256) void cvt_topk(
    const float* __restrict__ adj, unsigned int* __restrict__ bits,
    const float* __restrict__ x, const float* __restrict__ wqkv,
    const float* __restrict__ wout, const float* __restrict__ wff1,
    const float* __restrict__ wff2, unsigned short* __restrict__ xb,
    unsigned short* __restrict__ wqkvb, unsigned short* __restrict__ woutb,
    unsigned short* __restrict__ wff1b, unsigned short* __restrict__ wff2b) {
  __shared__ unsigned int hist[1024];
  __shared__ float cval[64];
  __shared__ int cidx[64];
  __shared__ int s_cnt, s_bb, s_need;
  __shared__ unsigned int rowbits[16];
  __shared__ int wsum[4];
  const int t = threadIdx.x;

  if (blockIdx.x >= 4096) {  // ---- cvt branch ----
    int i = ((blockIdx.x - 4096) * 256 + t) * 4;
    const float* src;
    unsigned short* dst;
    int off;
    if (i < 1048576)      { src = x;    dst = xb;    off = i; }
    else if (i < 1245184) { src = wqkv; dst = wqkvb; off = i - 1048576; }
    else if (i < 1310720) { src = wout; dst = woutb; off = i - 1245184; }
    else if (i < 1572864) { src = wff1; dst = wff1b; off = i - 1310720; }
    else                  { src = wff2; dst = wff2b; off = i - 1572864; }
    float4 v = *(const float4*)(src + off);
    ushort4 o;
    o.x = f2b(v.x); o.y = f2b(v.y); o.z = f2b(v.z); o.w = f2b(v.w);
    *(ushort4*)(dst + off) = o;
    return;
  }
  // ---- topk branch ----
  const int row = blockIdx.x;  // b*N + i
  const float* a = adj + (size_t)row * N_;
  const int lane = t & 63;
  const int wave = t >> 6;

  hist[t] = 0u; hist[t + 256] = 0u; hist[t + 512] = 0u; hist[t + 768] = 0u;
  if (t == 0) s_cnt = 0;
  float v0 = a[t];
  float v1 = a[t + 256];
  __syncthreads();
  const int b0 = min(1023, max(0, (int)(v0 * 1024.0f)));
  const int b1 = min(1023, max(0, (int)(v1 * 1024.0f)));
  atomicAdd(&hist[b0], 1u);
  atomicAdd(&hist[b1], 1u);
  __syncthreads();
  const int base = 1020 - 4 * t;
  const int h0 = (int)hist[base], h1 = (int)hist[base + 1];
  const int h2 = (int)hist[base + 2], h3 = (int)hist[base + 3];
  const int g = h0 + h1 + h2 + h3;
  int sc = g;
  #pragma unroll
  for (int off = 1; off < 64; off <<= 1) {
    int y = __shfl_up(sc, off);
    sc += (lane >= off) ? y : 0;
  }
  if (lane == 63) wsum[wave] = sc;
  __syncthreads();
  int wo = 0;
  for (int w = 0; w < wave; w++) wo += wsum[w];
  const int incl = sc + wo;
  const int excl = incl - g;
  if (excl < TOPK_ && incl >= TOPK_) {
    int cum = excl;
    int bb = base;
    const int hh[4] = {h3, h2, h1, h0};
    const int bs[4] = {base + 3, base + 2, base + 1, base};
    #pragma unroll
    for (int u = 0; u < 4; u++) {
      if (cum + hh[u] >= TOPK_) { bb = bs[u]; break; }
      cum += hh[u];
    }
    s_bb = bb;
    s_need = TOPK_ - cum;
  }
  __syncthreads();
  const int bb = s_bb;
  const int need = s_need;
  const bool sel0 = (b0 > bb);
  const bool sel1 = (b1 > bb);
  if (b0 == bb) { int p = atomicAdd(&s_cnt, 1); if (p < 64) { cval[p] = v0; cidx[p] = t; } }
  if (b1 == bb) { int p = atomicAdd(&s_cnt, 1); if (p < 64) { cval[p] = v1; cidx[p] = t + 256; } }
  unsigned long long m0 = __ballot(sel0);
  unsigned long long m1 = __ballot(sel1);
  if (lane == 0) {
    rowbits[2 * wave + 0] = (unsigned int)m0;
    rowbits[2 * wave + 1] = (unsigned int)(m0 >> 32);
    rowbits[8 + 2 * wave + 0] = (unsigned int)m1;
    rowbits[8 + 2 * wave + 1] = (unsigned int)(m1 >> 32);
  }
  __syncthreads();
  const int cnt = min(s_cnt, 64);
  for (int c = t; c < cnt; c += 256) {
    const float v = cval[c];
    const int idx = cidx[c];
    int r = 0;
    for (int j = 0; j < cnt; j++) {
      const float vj = cval[j];
      const int ij = cidx[j];
      if (vj > v || (vj == v && ij < idx)) r++;
    }
    if (r < need) atomicOr(&rowbits[idx >> 5], 1u << (idx & 31));
  }
  __syncthreads();
  if (t < 16) bits[(size_t)row * 16 + t] = rowbits[t];
}

// ---------------- gemm tile (R6-proven): C64x64 = A[64,K]*W[64,K]^T ----------------
// flags: 1=relu, 2=bf16 out, 4=qkv routing (Q->qb, K->kG frag, V->vG frag)
__device__ __forceinline__ void gemm_tile(
    unsigned short* __restrict__ Af, unsigned short* __restrict__ Wf,
    const unsigned short* __restrict__ A, const unsigned short* __restrict__ W,
    const float* __restrict__ bias, const float* __restrict__ res,
    void* __restrict__ Cout, unsigned short* __restrict__ qb,
    unsigned short* __restrict__ kG, unsigned short* __restrict__ vG,
    int bx, int by, int N, int K, int flags) {
  const int tid = threadIdx.x;
  const int m0 = by * 64, n0 = bx * 64;
  const int wave = tid >> 6, lane = tid & 63;
  const int wm = wave & 1, wn = wave >> 1;
  const int q = lane >> 4, l15 = lane & 15;
  const int r = tid >> 2, c0 = tid & 3;

  f32x4 acc[2][2];
  #pragma unroll
  for (int i = 0; i < 2; i++)
    #pragma unroll
    for (int j = 0; j < 2; j++) acc[i][j] = (f32x4){0.f, 0.f, 0.f, 0.f};

  const size_t arow = (size_t)(m0 + r) * K;
  const size_t wrow = (size_t)(n0 + r) * K;
  for (int k0 = 0; k0 < K; k0 += 64) {
    uint4 a0 = *(const uint4*)(A + arow + k0 + c0 * 8);
    uint4 a1 = *(const uint4*)(A + arow + k0 + (c0 + 4) * 8);
    uint4 w0 = *(const uint4*)(W + wrow + k0 + c0 * 8);
    uint4 w1 = *(const uint4*)(W + wrow + k0 + (c0 + 4) * 8);
    __syncthreads();
    {
      int kc = c0 >> 2, qq = c0 & 3;
      int s0 = ((r >> 4) * 2 + kc) * 64 + (r & 15) + qq * 16;
      int kc1 = (c0 + 4) >> 2, qq1 = (c0 + 4) & 3;
      int s1 = ((r >> 4) * 2 + kc1) * 64 + (r & 15) + qq1 * 16;
      *(uint4*)(Af + s0 * 8) = a0;
      *(uint4*)(Af + s1 * 8) = a1;
      *(uint4*)(Wf + s0 * 8) = w0;
      *(uint4*)(Wf + s1 * 8) = w1;
    }
    __syncthreads();
    #pragma unroll
    for (int kc = 0; kc < 2; kc++) {
      bf16x8 af[2], wf[2];
      #pragma unroll
      for (int mt = 0; mt < 2; mt++)
        af[mt] = *(const bf16x8*)(Af + (((wm * 2 + mt) * 2 + kc) * 64 + lane) * 8);
      #pragma unroll
      for (int nt = 0; nt < 2; nt++)
        wf[nt] = *(const bf16x8*)(Wf + (((wn * 2 + nt) * 2 + kc) * 64 + lane) * 8);
      #pragma unroll
      for (int mt = 0; mt < 2; mt++)
        #pragma unroll
        for (int nt = 0; nt < 2; nt++)
          acc[mt][nt] = __builtin_amdgcn_mfma_f32_16x16x32_bf16(af[mt], wf[nt], acc[mt][nt], 0, 0, 0);
    }
  }
  #pragma unroll
  for (int nt = 0; nt < 2; nt++) {
    const int col = n0 + (wn * 2 + nt) * 16 + l15;
    const float bv = bias[col];
    #pragma unroll
    for (int mt = 0; mt < 2; mt++) {
      const int rowb = m0 + (wm * 2 + mt) * 16 + q * 4;
      float ov[4];
      #pragma unroll
      for (int reg = 0; reg < 4; reg++) {
        float o = acc[mt][nt][reg] + bv;
        if (res) o += res[(size_t)(rowb + reg) * N + col];
        if (flags & 1) o = fmaxf(o, 0.f);
        ov[reg] = o;
      }
      if (flags & 4) {
        if (col < 256) {                          // Q -> row-major [M][256]
          #pragma unroll
          for (int reg = 0; reg < 4; reg++)
            qb[(size_t)(rowb + reg) * 256 + col] = f2b(ov[reg]);
        } else if (col < 512) {                   // K -> frag-order
          const int dfull = col - 256;
          const int hh2 = dfull >> 5, d = dfull & 31;
          const int q2 = d >> 3, sub = d & 7;
          const int bidx = rowb >> 9, j = rowb & 511;
          const int jt = j >> 6, jtile = (j >> 4) & 3, jl = j & 15;
          unsigned short* kp = kG +
              ((size_t)(((bidx * 8 + hh2) * 8 + jt) * 4 + jtile) * 64 + q2 * 16 + jl) * 8 + sub;
          kp[0] = f2b(ov[0]); kp[8] = f2b(ov[1]); kp[16] = f2b(ov[2]); kp[24] = f2b(ov[3]);
        } else {                                  // V -> frag-order
          const int dfull = col - 512;
          const int hh2 = dfull >> 5, d = dfull & 31;
          const int dt = d >> 4, dl = d & 15;
          const int bidx = rowb >> 9, j = rowb & 511;
          const int jt = j >> 6, jj = j & 63;
          const int kc = jj >> 5, q2 = (jj >> 3) & 3, sub0 = jj & 7;
          ushort4 st;
          st.x = f2b(ov[0]); st.y = f2b(ov[1]); st.z = f2b(ov[2]); st.w = f2b(ov[3]);
          *(ushort4*)(vG +
              ((size_t)(((bidx * 8 + hh2) * 8 + jt) * 4 + dt * 2 + kc) * 64 + q2 * 16 + dl) * 8 + sub0) = st;
        }
      } else if (flags & 2) {
        #pragma unroll
        for (int reg = 0; reg < 4; reg++)
          ((unsigned short*)Cout)[(size_t)(rowb + reg) * N + col] = f2b(ov[reg]);
      } else {
        #pragma unroll
        for (int reg = 0; reg < 4; reg++)
          ((float*)Cout)[(size_t)(rowb + reg) * N + col] = ov[reg];
      }
    }
  }
}

// ---------------- attention tile (R6-proven) ----------------
__device__ __forceinline__ void attn_tile(
    unsigned int* __restrict__ mrow, unsigned short* __restrict__ pFb,
    int bx, const unsigned short* __restrict__ qbuf,
    const unsigned short* __restrict__ kG, const unsigned short* __restrict__ vG,
    const unsigned int* __restrict__ bits, const float* __restrict__ emb,
    unsigned short* __restrict__ ctxo) {
  const int ib = bx & 7;
  const int h = (bx >> 3) & 7;
  const int b = bx >> 6;
  const int tid = threadIdx.x;
  const int lane = tid & 63;
  const int wave = tid >> 6;
  const int q = lane >> 4, l15 = lane & 15;

  {
    int rr = tid >> 2, wq = tid & 3;
    uint4 mw = *(const uint4*)(bits + ((size_t)(b * N_ + ib * 64 + rr)) * 16 + wq * 4);
    *(uint4*)(mrow + rr * 16 + wq * 4) = mw;
  }
  __syncthreads();

  const int i0w = ib * 64 + wave * 16;
  const bf16x8 qf = *(const bf16x8*)(qbuf + ((size_t)(b * N_ + i0w + l15)) * 256 + h * HD_ + q * 8);
  const float delta = emb[1 * H_ + h] - emb[2 * H_ + h];
  const float scale = 0.17677669529663687f;  // 1/sqrt(32)

  float m_run[4], l_run[4];
  #pragma unroll
  for (int e = 0; e < 4; e++) { m_run[e] = -1e30f; l_run[e] = 0.f; }
  f32x4 cacc[2];
  cacc[0] = (f32x4){0.f, 0.f, 0.f, 0.f};
  cacc[1] = (f32x4){0.f, 0.f, 0.f, 0.f};

  unsigned short* pbase = pFb + wave * 1024;
  const unsigned short* kb = kG + (size_t)(b * 8 + h) * 8 * 4 * 512;
  const unsigned short* vb = vG + (size_t)(b * 8 + h) * 8 * 4 * 512;

  #pragma unroll 1
  for (int jt = 0; jt < 8; jt++) {
    f32x4 s4[4];
    #pragma unroll
    for (int jtile = 0; jtile < 4; jtile++) {
      bf16x8 kf = *(const bf16x8*)(kb + (size_t)(jt * 4 + jtile) * 512 + lane * 8);
      s4[jtile] = __builtin_amdgcn_mfma_f32_16x16x32_bf16(qf, kf, (f32x4){0.f, 0.f, 0.f, 0.f}, 0, 0, 0);
    }
    unsigned long long mw64[4];
    #pragma unroll
    for (int reg = 0; reg < 4; reg++)
      mw64[reg] = *(const unsigned long long*)(mrow + (wave * 16 + q * 4 + reg) * 16 + jt * 2);
    float smat[4][4];
    #pragma unroll
    for (int jtile = 0; jtile < 4; jtile++) {
      #pragma unroll
      for (int reg = 0; reg < 4; reg++) {
        unsigned int w = (jtile & 2) ? (unsigned int)(mw64[reg] >> 32) : (unsigned int)mw64[reg];
        bool allowed = ((w >> ((jtile & 1) * 16 + l15)) & 1u) != 0u;
        int ig = ib * 64 + wave * 16 + q * 4 + reg;
        int jg = jt * 64 + jtile * 16 + l15;
        float s = s4[jtile][reg] * scale + ((jg == ig) ? delta : 0.f);
        smat[jtile][reg] = allowed ? s : -INFINITY;
      }
    }
    float alpha[4], pmat[4][4];
    #pragma unroll
    for (int reg = 0; reg < 4; reg++) {
      float mloc = fmaxf(fmaxf(smat[0][reg], smat[1][reg]), fmaxf(smat[2][reg], smat[3][reg]));
      #pragma unroll
      for (int off = 1; off < 16; off <<= 1) mloc = fmaxf(mloc, __shfl_xor(mloc, off));
      float mnew = fmaxf(m_run[reg], mloc);
      alpha[reg] = __expf(m_run[reg] - mnew);
      m_run[reg] = mnew;
      float ps = 0.f;
      #pragma unroll
      for (int jtile = 0; jtile < 4; jtile++) {
        float p = __expf(smat[jtile][reg] - mnew);
        pmat[jtile][reg] = p;
        ps += p;
      }
      #pragma unroll
      for (int off = 1; off < 16; off <<= 1) ps += __shfl_xor(ps, off);
      l_run[reg] = l_run[reg] * alpha[reg] + ps;
      cacc[0][reg] *= alpha[reg];
      cacc[1][reg] *= alpha[reg];
    }
    #pragma unroll
    for (int jtile = 0; jtile < 4; jtile++) {
      int j_l = jtile * 16 + l15;
      int sl = ((j_l >> 5) * 64 + ((j_l >> 3) & 3) * 16) * 8 + (j_l & 7);
      #pragma unroll
      for (int reg = 0; reg < 4; reg++)
        pbase[sl + (q * 4 + reg) * 8] = f2b(pmat[jtile][reg]);
    }
    #pragma unroll
    for (int kc = 0; kc < 2; kc++) {
      bf16x8 pf = *(const bf16x8*)(pbase + (kc * 64 + lane) * 8);
      #pragma unroll
      for (int dt = 0; dt < 2; dt++) {
        bf16x8 vf = *(const bf16x8*)(vb + (size_t)(jt * 4 + dt * 2 + kc) * 512 + lane * 8);
        cacc[dt] = __builtin_amdgcn_mfma_f32_16x16x32_bf16(pf, vf, cacc[dt], 0, 0, 0);
      }
    }
  }
  #pragma unroll
  for (int reg = 0; reg < 4; reg++) {
    const float linv = 1.f / l_run[reg];
    const size_t row = (size_t)(b * N_ + i0w + q * 4 + reg);
    #pragma unroll
    for (int dt = 0; dt < 2; dt++)
      ctxo[row * E_ + h * HD_ + dt * 16 + l15] = f2b(cacc[dt][reg] * linv);
  }
}

// ---------------- LayerNorm row (R6-proven) ----------------
__device__ __forceinline__ void ln_row(
    float* __restrict__ red, int row, const float* __restrict__ t,
    const float* __restrict__ g, const float* __restrict__ be,
    float* __restrict__ xo, unsigned short* __restrict__ xbo) {
  const int tid = threadIdx.x;
  const int wave = tid >> 6, lane = tid & 63;
  float v = t[(size_t)row * 256 + tid];
  float s = v, s2 = v * v;
  #pragma unroll
  for (int off = 32; off > 0; off >>= 1) { s += __shfl_xor(s, off); s2 += __shfl_xor(s2, off); }
  __syncthreads();  // protect red reuse across loop iterations
  if (lane == 0) { red[wave] = s; red[4 + wave] = s2; }
  __syncthreads();
  s = red[0] + red[1] + red[2] + red[3];
  s2 = red[4] + red[5] + red[6] + red[7];
  float mean = s * (1.f / 256.f);
  float var = s2 * (1.f / 256.f) - mean * mean;
  float inv = rsqrtf(var + 1e-5f);
  float o = (v - mean) * inv * g[tid] + be[tid];
  xo[(size_t)row * 256 + tid] = o;
  xbo[(size_t)row * 256 + tid] = f2b(o);
}

// ---------------- LN2 + pooling partial over a 16-row chunk ----------------
__device__ __forceinline__ void ln2pool_chunk(
    float* __restrict__ red, int c, const float* __restrict__ t,
    const float* __restrict__ g, const float* __restrict__ be,
    const float* __restrict__ wp, const float* __restrict__ bp,
    float* __restrict__ partial, float* __restrict__ pwsum) {
  const int tid = threadIdx.x;
  const int wave = tid >> 6, lane = tid & 63;
  const float wpv = wp[tid];
  float pacc = 0.f, esum = 0.f;
  #pragma unroll 1
  for (int rr = 0; rr < 16; rr++) {
    const int row = c * 16 + rr;
    float v = t[(size_t)row * 256 + tid];
    float s = v, s2 = v * v;
    #pragma unroll
    for (int off = 32; off > 0; off >>= 1) { s += __shfl_xor(s, off); s2 += __shfl_xor(s2, off); }
    __syncthreads();
    if (lane == 0) { red[wave] = s; red[4 + wave] = s2; }
    __syncthreads();
    s = red[0] + red[1] + red[2] + red[3];
    s2 = red[4] + red[5] + red[6] + red[7];
    float mean = s * (1.f / 256.f);
    float var = s2 * (1.f / 256.f) - mean * mean;
    float inv = rsqrtf(var + 1e-5f);
    float o = (v - mean) * inv * g[tid] + be[tid];
    float d = o * wpv;
    #pragma unroll
    for (int off = 32; off > 0; off >>= 1) d += __shfl_xor(d, off);
    __syncthreads();
    if (lane == 0) red[wave] = d;
    __syncthreads();
    float dot = red[0] + red[1] + red[2] + red[3] + bp[0];
    float e = __expf(tanhf(dot));
    pacc += e * o;
    esum += e;
  }
  partial[(size_t)c * 256 + tid] = pacc;
  if (tid == 0) pwsum[c] = esum;
}

__device__ __forceinline__ void pool_final_task(
    int b, const float* __restrict__ partial, const float* __restrict__ pwsum,
    float* __restrict__ out) {
  const int tid = threadIdx.x;
  float acc = 0.f, wsv = 0.f;
  #pragma unroll
  for (int c = 0; c < 32; c++) acc += partial[(size_t)(b * 32 + c) * 256 + tid];
  #pragma unroll
  for (int c = 0; c < 32; c++) wsv += pwsum[b * 32 + c];
  out[b * 256 + tid] = acc / wsv;
}

// ---------------- the cooperative megakernel ----------------
__global__ __launch_bounds__(256, 2) void mega(MegaArgs a) {
  cg::grid_group gg = cg::this_grid();
  __shared__ __align__(16) SmemU sm;
  const int nb = gridDim.x, bid = blockIdx.x;

  for (int t = bid; t < 768; t += nb)   // P1: qkv GEMM (12 x 64 tiles)
    gemm_tile(sm.gm.Af, sm.gm.Wf, a.xb, a.wqkvb, a.b_qkv, nullptr, nullptr,
              a.qb, a.kG, a.vG, t % 12, t / 12, 768, 256, 4);
  gg.sync();
  for (int t = bid; t < 512; t += nb)   // P2: attention
    attn_tile(sm.at.mrow, &sm.at.pF[0][0], t, a.qb, a.kG, a.vG, a.bits, a.emb, a.ctxb);
  gg.sync();
  for (int t = bid; t < 256; t += nb)   // P3: out-proj GEMM + residual(x)
    gemm_tile(sm.gm.Af, sm.gm.Wf, a.ctxb, a.woutb, a.b_out, a.x, a.tbuf,
              nullptr, nullptr, nullptr, t % 4, t / 4, 256, 256, 0);
  gg.sync();
  for (int rw = bid; rw < 4096; rw += nb)  // P4: LN1
    ln_row(sm.ln.red, rw, a.tbuf, a.g1, a.be1, a.x1, a.x1b);
  gg.sync();
  for (int t = bid; t < 1024; t += nb)  // P5: ff1 GEMM + relu (16 x 64 tiles)
    gemm_tile(sm.gm.Af, sm.gm.Wf, a.x1b, a.wff1b, a.b_ff1, nullptr, a.hffb,
              nullptr, nullptr, nullptr, t % 16, t / 16, 1024, 256, 1 | 2);
  gg.sync();
  for (int t = bid; t < 256; t += nb)   // P6: ff2 GEMM + residual(x1)
    gemm_tile(sm.gm.Af, sm.gm.Wf, a.hffb, a.wff2b, a.b_ff2, a.x1, a.tbuf,
              nullptr, nullptr, nullptr, t % 4, t / 4, 256, 1024, 0);
  gg.sync();
  for (int c = bid; c < 256; c += nb)   // P7: LN2 + pool partial (x2 never stored)
    ln2pool_chunk(sm.ln.red, c, a.tbuf, a.g2, a.be2, a.wp, a.bp, a.partial, a.pwsum);
  gg.sync();
  for (int b = bid; b < 8; b += nb)     // P8: pool final
    pool_final_task(b, a.partial, a.pwsum, a.outp);
}

// ---------------- fallback wrappers (identical math, discrete launches) ----------
__global__ __launch_bounds__(256) void k_qkv(MegaArgs a) {
  __shared__ __align__(16) SmemGemm g;
  gemm_tile(g.Af, g.Wf, a.xb, a.wqkvb, a.b_qkv, nullptr, nullptr, a.qb, a.kG, a.vG,
            blockIdx.x, blockIdx.y, 768, 256, 4);
}
__global__ __launch_bounds__(256) void k_attn(MegaArgs a) {
  __shared__ __align__(16) SmemAttn s;
  attn_tile(s.mrow, &s.pF[0][0], blockIdx.x, a.qb, a.kG, a.vG, a.bits, a.emb, a.ctxb);
}
__global__ __launch_bounds__(256) void k_out(MegaArgs a) {
  __shared__ __align__(16) SmemGemm g;
  gemm_tile(g.Af, g.Wf, a.ctxb, a.woutb, a.b_out, a.x, a.tbuf, nullptr, nullptr, nullptr,
            blockIdx.x, blockIdx.y, 256, 256, 0);
}
__global__ __launch_bounds__(256) void k_ln1(MegaArgs a) {
  __shared__ float red[8];
  ln_row(red, blockIdx.x, a.tbuf, a.g1, a.be1, a.x1, a.x1b);
}
__global__ __launch_bounds__(256) void k_ff1(MegaArgs a) {
  __shared__ __align__(16) SmemGemm g;
  gemm_tile(g.Af, g.Wf, a.x1b, a.wff1b, a.b_ff1, nullptr, a.hffb, nullptr, nullptr, nullptr,
            blockIdx.x, blockIdx.y, 1024, 256, 1 | 2);
}
__global__ __launch_bounds__(256) void k_ff2(MegaArgs a) {
  __shared__ __align__(16) SmemGemm g;
  gemm_tile(g.Af, g.Wf, a.hffb, a.wff2b, a.b_ff2, a.x1, a.tbuf, nullptr, nullptr, nullptr,
            blockIdx.x, blockIdx.y, 256, 1024, 0);
}
__global__ __launch_bounds__(256) void k_ln2pool(MegaArgs a) {
  __shared__ float red[8];
  ln2pool_chunk(red, blockIdx.x, a.tbuf, a.g2, a.be2, a.wp, a.bp, a.partial, a.pwsum);
}
__global__ __launch_bounds__(256) void k_poolfinal(MegaArgs a) {
  pool_final_task(blockIdx.x, a.partial, a.pwsum, a.outp);
}

// ---------------- launch ----------------
extern "C" void kernel_launch(void* const* d_in, const int* in_sizes, int n_in,
                              void* d_out, int out_size, void* d_ws, size_t ws_size,
                              hipStream_t stream) {
  (void)in_sizes; (void)n_in; (void)out_size; (void)ws_size;
  const float* x      = (const float*)d_in[0];
  const float* adj    = (const float*)d_in[1];
  const float* emb    = (const float*)d_in[2];
  const float* w_qkv  = (const float*)d_in[3];
  const float* b_qkv  = (const float*)d_in[4];
  const float* w_out  = (const float*)d_in[5];
  const float* b_out  = (const float*)d_in[6];
  const float* w_ff1  = (const float*)d_in[7];
  const float* b_ff1  = (const float*)d_in[8];
  const float* w_ff2  = (const float*)d_in[9];
  const float* b_ff2  = (const float*)d_in[10];
  const float* g1     = (const float*)d_in[11];
  const float* be1    = (const float*)d_in[12];
  const float* g2     = (const float*)d_in[13];
  const float* be2    = (const float*)d_in[14];
  const float* w_pool = (const float*)d_in[15];
  const float* b_pool = (const float*)d_in[16];

  char* ws = (char*)d_ws;
  unsigned int*   bits  = (unsigned int*)ws;                       // 256 KB
  unsigned short* xb    = (unsigned short*)(ws + 262144);          // 2 MB
  unsigned short* qb    = (unsigned short*)(ws + 2359296);         // 2 MB
  unsigned short* kG    = (unsigned short*)(ws + 4456448);         // 2 MB
  unsigned short* vG    = (unsigned short*)(ws + 6553600);         // 2 MB
  unsigned short* ctxb  = (unsigned short*)(ws + 8650752);         // 2 MB
  float*          tbuf  = (float*)(ws + 10747904);                 // 4 MB (LN1 in; reused ff2 out)
  float*          x1    = (float*)(ws + 14942208);                 // 4 MB
  unsigned short* x1b   = (unsigned short*)(ws + 19136512);        // 2 MB
  unsigned short* hffb  = (unsigned short*)(ws + 21233664);        // 8 MB
  unsigned short* wqkvb = (unsigned short*)(ws + 29622272);        // 384 KB
  unsigned short* woutb = (unsigned short*)(ws + 30015488);        // 128 KB
  unsigned short* wff1b = (unsigned short*)(ws + 30146560);        // 512 KB
  unsigned short* wff2b = (unsigned short*)(ws + 30670848);        // 512 KB
  float*          partial = (float*)(ws + 31195136);               // 256 KB
  float*          pwsum   = (float*)(ws + 31457280);               // 1 KB
  float*          outp  = (float*)d_out;

  cvt_topk<<<4096 + 1792, 256, 0, stream>>>(adj, bits, x, w_qkv, w_out, w_ff1,
                                            w_ff2, xb, wqkvb, woutb, wff1b, wff2b);

  MegaArgs ma;
  ma.xb = xb; ma.wqkvb = wqkvb; ma.woutb = woutb; ma.wff1b = wff1b; ma.wff2b = wff2b;
  ma.bits = bits;
  ma.x = x; ma.emb = emb; ma.b_qkv = b_qkv; ma.b_out = b_out; ma.b_ff1 = b_ff1;
  ma.b_ff2 = b_ff2; ma.g1 = g1; ma.be1 = be1; ma.g2 = g2; ma.be2 = be2;
  ma.wp = w_pool; ma.bp = b_pool;
  ma.qb = qb; ma.kG = kG; ma.vG = vG; ma.ctxb = ctxb; ma.x1b = x1b; ma.hffb = hffb;
  ma.tbuf = tbuf; ma.x1 = x1; ma.partial = partial; ma.pwsum = pwsum; ma.outp = outp;

  void* kp[] = {&ma};
  hipError_t err = hipLaunchCooperativeKernel((void*)mega, dim3(512), dim3(256),
                                              kp, 0, stream);
  if (err != hipSuccess) {
    (void)hipGetLastError();  // clear sticky error; fall back to discrete pipeline
    k_qkv<<<dim3(12, 64), 256, 0, stream>>>(ma);
    k_attn<<<512, 256, 0, stream>>>(ma);
    k_out<<<dim3(4, 64), 256, 0, stream>>>(ma);
    k_ln1<<<4096, 256, 0, stream>>>(ma);
    k_ff1<<<dim3(16, 64), 256, 0, stream>>>(ma);
    k_ff2<<<dim3(4, 64), 256, 0, stream>>>(ma);
    k_ln2pool<<<256, 256, 0, stream>>>(ma);
    k_poolfinal<<<8, 256, 0, stream>>>(ma);
  }
}

// Round 9
// 176.687 us; speedup vs baseline: 3.3736x; 3.3736x over previous
//
#include <hip/hip_runtime.h>
#include <math.h>

// SubGraphTransformer: B=8,N=512,E=256,H=8,HD=32,FF=1024,TOPK=102.
// Floyd-Warshall is dead code: surviving (top-k) entries all have dist==1
// except the diagonal (dist==0); row-constant bias cancels under softmax, so
// only topk bitmask + per-head diagonal delta (emb[1][h]-emb[2][h]) matter.
// R3: bf16 MFMA. R4: pool parallelized. R5 (rev): uncoalesced frag gathers.
// R6: frag-order global K/V -> coalesced attn (177us). R7 (rev): GEMM+LN
// fusion died on occupancy + W re-read. R8 (rev): cooperative grid.sync()
// costs ~50-60us each on 8 non-coherent XCDs (L2 flush) -> 471us mega.
// R9: back to R6 discrete pipeline; only proven merges: cvt+topk one kernel,
// LN 8 rows/block, LN2+ew+pool-partial fused (x2 never materialized).

#define B_ 8
#define N_ 512
#define E_ 256
#define H_ 8
#define HD_ 32
#define TOPK_ 102

typedef __attribute__((ext_vector_type(8))) short bf16x8;
typedef __attribute__((ext_vector_type(4))) float f32x4;

__device__ __forceinline__ unsigned short f2b(float f) {  // fp32->bf16 RNE
  unsigned u = __builtin_bit_cast(unsigned, f);
  return (unsigned short)((u + 0x7FFFu + ((u >> 16) & 1u)) >> 16);
}

// ---------------- 1. fused cast + top-k ----------------
// blocks [0,4096): topk row; [4096,5888): cvt chunk.
__global__ __launch_bounds__(256) void cvt_topk(
    const float* __restrict__ adj, unsigned int* __restrict__ bits,
    const float* __restrict__ x, const float* __restrict__ wqkv,
    const float* __restrict__ wout, const float* __restrict__ wff1,
    const float* __restrict__ wff2, unsigned short* __restrict__ xb,
    unsigned short* __restrict__ wqkvb, unsigned short* __restrict__ woutb,
    unsigned short* __restrict__ wff1b, unsigned short* __restrict__ wff2b) {
  __shared__ unsigned int hist[1024];
  __shared__ float cval[64];
  __shared__ int cidx[64];
  __shared__ int s_cnt, s_bb, s_need;
  __shared__ unsigned int rowbits[16];
  __shared__ int wsum[4];
  const int t = threadIdx.x;

  if (blockIdx.x >= 4096) {  // ---- cvt branch ----
    int i = ((blockIdx.x - 4096) * 256 + t) * 4;
    const float* src;
    unsigned short* dst;
    int off;
    if (i < 1048576)      { src = x;    dst = xb;    off = i; }
    else if (i < 1245184) { src = wqkv; dst = wqkvb; off = i - 1048576; }
    else if (i < 1310720) { src = wout; dst = woutb; off = i - 1245184; }
    else if (i < 1572864) { src = wff1; dst = wff1b; off = i - 1310720; }
    else                  { src = wff2; dst = wff2b; off = i - 1572864; }
    float4 v = *(const float4*)(src + off);
    ushort4 o;
    o.x = f2b(v.x); o.y = f2b(v.y); o.z = f2b(v.z); o.w = f2b(v.w);
    *(ushort4*)(dst + off) = o;
    return;
  }
  // ---- topk branch ----
  const int row = blockIdx.x;  // b*N + i
  const float* a = adj + (size_t)row * N_;
  const int lane = t & 63;
  const int wave = t >> 6;

  hist[t] = 0u; hist[t + 256] = 0u; hist[t + 512] = 0u; hist[t + 768] = 0u;
  if (t == 0) s_cnt = 0;
  float v0 = a[t];
  float v1 = a[t + 256];
  __syncthreads();
  const int b0 = min(1023, max(0, (int)(v0 * 1024.0f)));
  const int b1 = min(1023, max(0, (int)(v1 * 1024.0f)));
  atomicAdd(&hist[b0], 1u);
  atomicAdd(&hist[b1], 1u);
  __syncthreads();
  const int base = 1020 - 4 * t;
  const int h0 = (int)hist[base], h1 = (int)hist[base + 1];
  const int h2 = (int)hist[base + 2], h3 = (int)hist[base + 3];
  const int g = h0 + h1 + h2 + h3;
  int sc = g;
  #pragma unroll
  for (int off = 1; off < 64; off <<= 1) {
    int y = __shfl_up(sc, off);
    sc += (lane >= off) ? y : 0;
  }
  if (lane == 63) wsum[wave] = sc;
  __syncthreads();
  int wo = 0;
  for (int w = 0; w < wave; w++) wo += wsum[w];
  const int incl = sc + wo;
  const int excl = incl - g;
  if (excl < TOPK_ && incl >= TOPK_) {
    int cum = excl;
    int bb = base;
    const int hh[4] = {h3, h2, h1, h0};
    const int bs[4] = {base + 3, base + 2, base + 1, base};
    #pragma unroll
    for (int u = 0; u < 4; u++) {
      if (cum + hh[u] >= TOPK_) { bb = bs[u]; break; }
      cum += hh[u];
    }
    s_bb = bb;
    s_need = TOPK_ - cum;
  }
  __syncthreads();
  const int bb = s_bb;
  const int need = s_need;
  const bool sel0 = (b0 > bb);
  const bool sel1 = (b1 > bb);
  if (b0 == bb) { int p = atomicAdd(&s_cnt, 1); if (p < 64) { cval[p] = v0; cidx[p] = t; } }
  if (b1 == bb) { int p = atomicAdd(&s_cnt, 1); if (p < 64) { cval[p] = v1; cidx[p] = t + 256; } }
  unsigned long long m0 = __ballot(sel0);
  unsigned long long m1 = __ballot(sel1);
  if (lane == 0) {
    rowbits[2 * wave + 0] = (unsigned int)m0;
    rowbits[2 * wave + 1] = (unsigned int)(m0 >> 32);
    rowbits[8 + 2 * wave + 0] = (unsigned int)m1;
    rowbits[8 + 2 * wave + 1] = (unsigned int)(m1 >> 32);
  }
  __syncthreads();
  const int cnt = min(s_cnt, 64);
  for (int c = t; c < cnt; c += 256) {
    const float v = cval[c];
    const int idx = cidx[c];
    int r = 0;
    for (int j = 0; j < cnt; j++) {
      const float vj = cval[j];
      const int ij = cidx[j];
      if (vj > v || (vj == v && ij < idx)) r++;
    }
    if (r < need) atomicOr(&rowbits[idx >> 5], 1u << (idx & 31));
  }
  __syncthreads();
  if (t < 16) bits[(size_t)row * 16 + t] = rowbits[t];
}

// ---------------- 2. bf16 MFMA GEMM: C[M,N] = A[M,K]*W[N,K]^T + bias ----------------
// flags: 1=relu, 2=bf16 output, 4=qkv routing (Q->Cout dense [M][256],
// K->kG frag-order, V->vG frag-order).
__global__ __launch_bounds__(256) void gemm_mfma(
    const unsigned short* __restrict__ A, const unsigned short* __restrict__ W,
    const float* __restrict__ bias, const float* __restrict__ res,
    void* __restrict__ Cout, unsigned short* __restrict__ kG,
    unsigned short* __restrict__ vG, int M, int N, int K, int flags) {
  __shared__ __align__(16) unsigned short Af[8 * 64 * 8];
  __shared__ __align__(16) unsigned short Wf[8 * 64 * 8];
  const int tid = threadIdx.x;
  const int m0 = blockIdx.y * 64, n0 = blockIdx.x * 64;
  const int wave = tid >> 6, lane = tid & 63;
  const int wm = wave & 1, wn = wave >> 1;
  const int q = lane >> 4, l15 = lane & 15;
  const int r = tid >> 2, c0 = tid & 3;

  f32x4 acc[2][2];
  #pragma unroll
  for (int i = 0; i < 2; i++)
    #pragma unroll
    for (int j = 0; j < 2; j++) acc[i][j] = (f32x4){0.f, 0.f, 0.f, 0.f};

  const size_t arow = (size_t)(m0 + r) * K;
  const size_t wrow = (size_t)(n0 + r) * K;
  for (int k0 = 0; k0 < K; k0 += 64) {
    uint4 a0 = *(const uint4*)(A + arow + k0 + c0 * 8);
    uint4 a1 = *(const uint4*)(A + arow + k0 + (c0 + 4) * 8);
    uint4 w0 = *(const uint4*)(W + wrow + k0 + c0 * 8);
    uint4 w1 = *(const uint4*)(W + wrow + k0 + (c0 + 4) * 8);
    __syncthreads();
    {
      int kc = c0 >> 2, qq = c0 & 3;
      int s0 = ((r >> 4) * 2 + kc) * 64 + (r & 15) + qq * 16;
      int kc1 = (c0 + 4) >> 2, qq1 = (c0 + 4) & 3;
      int s1 = ((r >> 4) * 2 + kc1) * 64 + (r & 15) + qq1 * 16;
      *(uint4*)(Af + s0 * 8) = a0;
      *(uint4*)(Af + s1 * 8) = a1;
      *(uint4*)(Wf + s0 * 8) = w0;
      *(uint4*)(Wf + s1 * 8) = w1;
    }
    __syncthreads();
    #pragma unroll
    for (int kc = 0; kc < 2; kc++) {
      bf16x8 af[2], wf[2];
      #pragma unroll
      for (int mt = 0; mt < 2; mt++)
        af[mt] = *(const bf16x8*)(Af + (((wm * 2 + mt) * 2 + kc) * 64 + lane) * 8);
      #pragma unroll
      for (int nt = 0; nt < 2; nt++)
        wf[nt] = *(const bf16x8*)(Wf + (((wn * 2 + nt) * 2 + kc) * 64 + lane) * 8);
      #pragma unroll
      for (int mt = 0; mt < 2; mt++)
        #pragma unroll
        for (int nt = 0; nt < 2; nt++)
          acc[mt][nt] = __builtin_amdgcn_mfma_f32_16x16x32_bf16(af[mt], wf[nt], acc[mt][nt], 0, 0, 0);
    }
  }
  #pragma unroll
  for (int nt = 0; nt < 2; nt++) {
    const int col = n0 + (wn * 2 + nt) * 16 + l15;
    const float bv = bias[col];
    #pragma unroll
    for (int mt = 0; mt < 2; mt++) {
      const int rowb = m0 + (wm * 2 + mt) * 16 + q * 4;
      float ov[4];
      #pragma unroll
      for (int reg = 0; reg < 4; reg++) {
        float o = acc[mt][nt][reg] + bv;
        if (res) o += res[(size_t)(rowb + reg) * N + col];
        if (flags & 1) o = fmaxf(o, 0.f);
        ov[reg] = o;
      }
      if (flags & 4) {
        if (col < 256) {                          // Q -> dense row-major [M][256]
          #pragma unroll
          for (int reg = 0; reg < 4; reg++)
            ((unsigned short*)Cout)[(size_t)(rowb + reg) * 256 + col] = f2b(ov[reg]);
        } else if (col < 512) {                   // K -> frag-order
          const int dfull = col - 256;
          const int hh2 = dfull >> 5, d = dfull & 31;
          const int q2 = d >> 3, sub = d & 7;
          const int bidx = rowb >> 9, j = rowb & 511;
          const int jt = j >> 6, jtile = (j >> 4) & 3, jl = j & 15;
          unsigned short* kp = kG +
              ((size_t)(((bidx * 8 + hh2) * 8 + jt) * 4 + jtile) * 64 + q2 * 16 + jl) * 8 + sub;
          kp[0] = f2b(ov[0]); kp[8] = f2b(ov[1]); kp[16] = f2b(ov[2]); kp[24] = f2b(ov[3]);
        } else {                                  // V -> frag-order
          const int dfull = col - 512;
          const int hh2 = dfull >> 5, d = dfull & 31;
          const int dt = d >> 4, dl = d & 15;
          const int bidx = rowb >> 9, j = rowb & 511;
          const int jt = j >> 6, jj = j & 63;
          const int kc = jj >> 5, q2 = (jj >> 3) & 3, sub0 = jj & 7;
          ushort4 st;
          st.x = f2b(ov[0]); st.y = f2b(ov[1]); st.z = f2b(ov[2]); st.w = f2b(ov[3]);
          *(ushort4*)(vG +
              ((size_t)(((bidx * 8 + hh2) * 8 + jt) * 4 + dt * 2 + kc) * 64 + q2 * 16 + dl) * 8 + sub0) = st;
        }
      } else if (flags & 2) {
        #pragma unroll
        for (int reg = 0; reg < 4; reg++)
          ((unsigned short*)Cout)[(size_t)(rowb + reg) * N + col] = f2b(ov[reg]);
      } else {
        #pragma unroll
        for (int reg = 0; reg < 4; reg++)
          ((float*)Cout)[(size_t)(rowb + reg) * N + col] = ov[reg];
      }
    }
  }
}

// ---------------- 3. masked flash attention, bf16 MFMA (R6-proven) ----------------
__global__ __launch_bounds__(256) void attn_mfma(
    const unsigned short* __restrict__ qb, const unsigned short* __restrict__ kG,
    const unsigned short* __restrict__ vG, const unsigned int* __restrict__ bits,
    const float* __restrict__ emb, unsigned short* __restrict__ ctxo) {
  const int bx = blockIdx.x;
  const int ib = bx & 7;
  const int h = (bx >> 3) & 7;
  const int b = bx >> 6;
  const int tid = threadIdx.x;
  const int lane = tid & 63;
  const int wave = tid >> 6;
  const int q = lane >> 4, l15 = lane & 15;

  __shared__ __align__(16) unsigned int mrow[64 * 16];
  __shared__ __align__(16) unsigned short pF[4][2 * 64 * 8];

  {
    int rr = tid >> 2, wq = tid & 3;
    uint4 mw = *(const uint4*)(bits + ((size_t)(b * N_ + ib * 64 + rr)) * 16 + wq * 4);
    *(uint4*)(mrow + rr * 16 + wq * 4) = mw;
  }
  __syncthreads();

  const int i0w = ib * 64 + wave * 16;
  const bf16x8 qf = *(const bf16x8*)(qb + ((size_t)(b * N_ + i0w + l15)) * 256 + h * HD_ + q * 8);
  const float delta = emb[1 * H_ + h] - emb[2 * H_ + h];
  const float scale = 0.17677669529663687f;  // 1/sqrt(32)

  float m_run[4], l_run[4];
  #pragma unroll
  for (int e = 0; e < 4; e++) { m_run[e] = -1e30f; l_run[e] = 0.f; }
  f32x4 cacc[2];
  cacc[0] = (f32x4){0.f, 0.f, 0.f, 0.f};
  cacc[1] = (f32x4){0.f, 0.f, 0.f, 0.f};

  unsigned short* pbase = &pF[wave][0];
  const unsigned short* kb = kG + (size_t)(b * 8 + h) * 8 * 4 * 512;
  const unsigned short* vb = vG + (size_t)(b * 8 + h) * 8 * 4 * 512;

  #pragma unroll 1
  for (int jt = 0; jt < 8; jt++) {
    f32x4 s4[4];
    #pragma unroll
    for (int jtile = 0; jtile < 4; jtile++) {
      bf16x8 kf = *(const bf16x8*)(kb + (size_t)(jt * 4 + jtile) * 512 + lane * 8);
      s4[jtile] = __builtin_amdgcn_mfma_f32_16x16x32_bf16(qf, kf, (f32x4){0.f, 0.f, 0.f, 0.f}, 0, 0, 0);
    }
    unsigned long long mw64[4];
    #pragma unroll
    for (int reg = 0; reg < 4; reg++)
      mw64[reg] = *(const unsigned long long*)(mrow + (wave * 16 + q * 4 + reg) * 16 + jt * 2);
    float smat[4][4];
    #pragma unroll
    for (int jtile = 0; jtile < 4; jtile++) {
      #pragma unroll
      for (int reg = 0; reg < 4; reg++) {
        unsigned int w = (jtile & 2) ? (unsigned int)(mw64[reg] >> 32) : (unsigned int)mw64[reg];
        bool allowed = ((w >> ((jtile & 1) * 16 + l15)) & 1u) != 0u;
        int ig = ib * 64 + wave * 16 + q * 4 + reg;
        int jg = jt * 64 + jtile * 16 + l15;
        float s = s4[jtile][reg] * scale + ((jg == ig) ? delta : 0.f);
        smat[jtile][reg] = allowed ? s : -INFINITY;
      }
    }
    float alpha[4], pmat[4][4];
    #pragma unroll
    for (int reg = 0; reg < 4; reg++) {
      float mloc = fmaxf(fmaxf(smat[0][reg], smat[1][reg]), fmaxf(smat[2][reg], smat[3][reg]));
      #pragma unroll
      for (int off = 1; off < 16; off <<= 1) mloc = fmaxf(mloc, __shfl_xor(mloc, off));
      float mnew = fmaxf(m_run[reg], mloc);
      alpha[reg] = __expf(m_run[reg] - mnew);
      m_run[reg] = mnew;
      float ps = 0.f;
      #pragma unroll
      for (int jtile = 0; jtile < 4; jtile++) {
        float p = __expf(smat[jtile][reg] - mnew);
        pmat[jtile][reg] = p;
        ps += p;
      }
      #pragma unroll
      for (int off = 1; off < 16; off <<= 1) ps += __shfl_xor(ps, off);
      l_run[reg] = l_run[reg] * alpha[reg] + ps;
      cacc[0][reg] *= alpha[reg];
      cacc[1][reg] *= alpha[reg];
    }
    #pragma unroll
    for (int jtile = 0; jtile < 4; jtile++) {
      int j_l = jtile * 16 + l15;
      int sl = ((j_l >> 5) * 64 + ((j_l >> 3) & 3) * 16) * 8 + (j_l & 7);
      #pragma unroll
      for (int reg = 0; reg < 4; reg++)
        pbase[sl + (q * 4 + reg) * 8] = f2b(pmat[jtile][reg]);
    }
    #pragma unroll
    for (int kc = 0; kc < 2; kc++) {
      bf16x8 pf = *(const bf16x8*)(pbase + (kc * 64 + lane) * 8);
      #pragma unroll
      for (int dt = 0; dt < 2; dt++) {
        bf16x8 vf = *(const bf16x8*)(vb + (size_t)(jt * 4 + dt * 2 + kc) * 512 + lane * 8);
        cacc[dt] = __builtin_amdgcn_mfma_f32_16x16x32_bf16(pf, vf, cacc[dt], 0, 0, 0);
      }
    }
  }
  #pragma unroll
  for (int reg = 0; reg < 4; reg++) {
    const float linv = 1.f / l_run[reg];
    const size_t row = (size_t)(b * N_ + i0w + q * 4 + reg);
    #pragma unroll
    for (int dt = 0; dt < 2; dt++)
      ctxo[row * E_ + h * HD_ + dt * 16 + l15] = f2b(cacc[dt][reg] * linv);
  }
}

// ---------------- 4. LayerNorm, 8 rows per block ----------------
__global__ __launch_bounds__(256) void ln8_kernel(
    const float* __restrict__ t, const float* __restrict__ g,
    const float* __restrict__ be, float* __restrict__ out,
    unsigned short* __restrict__ outb) {
  __shared__ float sh[8];
  const int tid = threadIdx.x;
  const int wave = tid >> 6, lane = tid & 63;
  const float gv = g[tid], bev = be[tid];
  #pragma unroll 1
  for (int rr = 0; rr < 8; rr++) {
    const int row = blockIdx.x * 8 + rr;
    float v = t[(size_t)row * E_ + tid];
    float s = v, s2 = v * v;
    #pragma unroll
    for (int off = 32; off > 0; off >>= 1) {
      s += __shfl_xor(s, off);
      s2 += __shfl_xor(s2, off);
    }
    __syncthreads();  // protect sh reuse across rows
    if (lane == 0) { sh[wave] = s; sh[4 + wave] = s2; }
    __syncthreads();
    s = sh[0] + sh[1] + sh[2] + sh[3];
    s2 = sh[4] + sh[5] + sh[6] + sh[7];
    float mean = s * (1.f / 256.f);
    float var = s2 * (1.f / 256.f) - mean * mean;
    float inv = rsqrtf(var + 1e-5f);
    float o = (v - mean) * inv * gv + bev;
    out[(size_t)row * E_ + tid] = o;
    outb[(size_t)row * E_ + tid] = f2b(o);
  }
}

// ---------------- 5. LN2 + ew + pooling partial, 8 rows per block ----------------
// x2 never materialized: partial[c][256] = sum_r ew_r * x2_r, pwsum[c] = sum ew.
__global__ __launch_bounds__(256) void ln2pool_kernel(
    const float* __restrict__ t, const float* __restrict__ g,
    const float* __restrict__ be, const float* __restrict__ wp,
    const float* __restrict__ bp, float* __restrict__ partial,
    float* __restrict__ pwsum) {
  __shared__ float sh[8];
  const int tid = threadIdx.x;
  const int wave = tid >> 6, lane = tid & 63;
  const int c = blockIdx.x;
  const float gv = g[tid], bev = be[tid], wpv = wp[tid], bpv = bp[0];
  float pacc = 0.f, esum = 0.f;
  #pragma unroll 1
  for (int rr = 0; rr < 8; rr++) {
    const int row = c * 8 + rr;
    float v = t[(size_t)row * E_ + tid];
    float s = v, s2 = v * v;
    #pragma unroll
    for (int off = 32; off > 0; off >>= 1) {
      s += __shfl_xor(s, off);
      s2 += __shfl_xor(s2, off);
    }
    __syncthreads();
    if (lane == 0) { sh[wave] = s; sh[4 + wave] = s2; }
    __syncthreads();
    s = sh[0] + sh[1] + sh[2] + sh[3];
    s2 = sh[4] + sh[5] + sh[6] + sh[7];
    float mean = s * (1.f / 256.f);
    float var = s2 * (1.f / 256.f) - mean * mean;
    float inv = rsqrtf(var + 1e-5f);
    float o = (v - mean) * inv * gv + bev;
    float d = o * wpv;
    #pragma unroll
    for (int off = 32; off > 0; off >>= 1) d += __shfl_xor(d, off);
    __syncthreads();
    if (lane == 0) sh[wave] = d;
    __syncthreads();
    float dot = sh[0] + sh[1] + sh[2] + sh[3] + bpv;
    float e = __expf(tanhf(dot));
    pacc += e * o;
    esum += e;
  }
  partial[(size_t)c * E_ + tid] = pacc;
  if (tid == 0) pwsum[c] = esum;
}

// ---------------- 6. pooling final reduce (64 chunks per batch) ----------------
__global__ __launch_bounds__(256) void pool_final(
    const float* __restrict__ partial, const float* __restrict__ pwsum,
    float* __restrict__ out) {
  const int b = blockIdx.x;
  const int tid = threadIdx.x;
  float acc = 0.f, ws = 0.f;
  #pragma unroll
  for (int c = 0; c < 64; c++) acc += partial[(size_t)(b * 64 + c) * E_ + tid];
  #pragma unroll
  for (int c = 0; c < 64; c++) ws += pwsum[b * 64 + c];
  out[b * E_ + tid] = acc / ws;
}

// ---------------- launch ----------------
extern "C" void kernel_launch(void* const* d_in, const int* in_sizes, int n_in,
                              void* d_out, int out_size, void* d_ws, size_t ws_size,
                              hipStream_t stream) {
  (void)in_sizes; (void)n_in; (void)out_size; (void)ws_size;
  const float* x      = (const float*)d_in[0];
  const float* adj    = (const float*)d_in[1];
  const float* emb    = (const float*)d_in[2];
  const float* w_qkv  = (const float*)d_in[3];
  const float* b_qkv  = (const float*)d_in[4];
  const float* w_out  = (const float*)d_in[5];
  const float* b_out  = (const float*)d_in[6];
  const float* w_ff1  = (const float*)d_in[7];
  const float* b_ff1  = (const float*)d_in[8];
  const float* w_ff2  = (const float*)d_in[9];
  const float* b_ff2  = (const float*)d_in[10];
  const float* g1     = (const float*)d_in[11];
  const float* be1    = (const float*)d_in[12];
  const float* g2     = (const float*)d_in[13];
  const float* be2    = (const float*)d_in[14];
  const float* w_pool = (const float*)d_in[15];
  const float* b_pool = (const float*)d_in[16];

  char* ws = (char*)d_ws;
  unsigned int*   bits  = (unsigned int*)ws;                       // 256 KB
  unsigned short* xb    = (unsigned short*)(ws + 262144);          // 2 MB
  unsigned short* qb    = (unsigned short*)(ws + 2359296);         // 2 MB [M][256]
  unsigned short* kG    = (unsigned short*)(ws + 4456448);         // 2 MB frag-order
  unsigned short* vG    = (unsigned short*)(ws + 6553600);         // 2 MB frag-order
  unsigned short* ctxb  = (unsigned short*)(ws + 8650752);         // 2 MB
  float*          tbuf  = (float*)(ws + 10747904);                 // 4 MB
  float*          x1    = (float*)(ws + 14942208);                 // 4 MB
  unsigned short* x1b   = (unsigned short*)(ws + 19136512);        // 2 MB
  unsigned short* hffb  = (unsigned short*)(ws + 21233664);        // 8 MB
  unsigned short* wqkvb = (unsigned short*)(ws + 29622272);        // 384 KB
  unsigned short* woutb = (unsigned short*)(ws + 30015488);        // 128 KB
  unsigned short* wff1b = (unsigned short*)(ws + 30146560);        // 512 KB
  unsigned short* wff2b = (unsigned short*)(ws + 30670848);        // 512 KB
  float*          partial = (float*)(ws + 31195136);               // 512 KB
  float*          pwsum   = (float*)(ws + 31719424);               // 2 KB
  float*          outp  = (float*)d_out;

  const int M = B_ * N_;  // 4096

  cvt_topk<<<4096 + 1792, 256, 0, stream>>>(adj, bits, x, w_qkv, w_out, w_ff1,
                                            w_ff2, xb, wqkvb, woutb, wff1b, wff2b);
  gemm_mfma<<<dim3(768 / 64, M / 64), 256, 0, stream>>>(
      xb, wqkvb, b_qkv, nullptr, qb, kG, vG, M, 768, E_, 4);
  attn_mfma<<<B_ * H_ * (N_ / 64), 256, 0, stream>>>(qb, kG, vG, bits, emb, ctxb);
  gemm_mfma<<<dim3(E_ / 64, M / 64), 256, 0, stream>>>(
      ctxb, woutb, b_out, x, tbuf, nullptr, nullptr, M, E_, E_, 0);
  ln8_kernel<<<M / 8, 256, 0, stream>>>(tbuf, g1, be1, x1, x1b);
  gemm_mfma<<<dim3(1024 / 64, M / 64), 256, 0, stream>>>(
      x1b, wff1b, b_ff1, nullptr, hffb, nullptr, nullptr, M, 1024, E_, 1 | 2);
  gemm_mfma<<<dim3(E_ / 64, M / 64), 256, 0, stream>>>(
      hffb, wff2b, b_ff2, x1, tbuf, nullptr, nullptr, M, E_, 1024, 0);
  ln2pool_kernel<<<M / 8, 256, 0, stream>>>(tbuf, g2, be2, w_pool, b_pool,
                                            partial, pwsum);
  pool_final<<<B_, 256, 0, stream>>>(partial, pwsum, outp);
}